// Round 2
// baseline (271.413 us; speedup 1.0000x reference)
//
#include <hip/hip_runtime.h>

#define NCTX 4096
#define DMODEL 2048
#define DHEAD 128

typedef _Float16 f16;
typedef f16 f16x8 __attribute__((ext_vector_type(8)));
typedef float f32x4 __attribute__((ext_vector_type(4)));
typedef unsigned short u16;
typedef u16 u16x8 __attribute__((ext_vector_type(8)));

__device__ __forceinline__ u16 f2h(float f) {
  union { f16 h; u16 u; } v; v.h = (f16)f; return v.u;
}
__device__ __forceinline__ float h2f(u16 u) {
  union { u16 u; f16 h; } v; v.u = u; return (float)v.h;
}

__device__ __forceinline__ void gl_lds16(const void* g, void* l) {
  __builtin_amdgcn_global_load_lds((const __attribute__((address_space(1))) void*)g,
                                   (__attribute__((address_space(3))) void*)l, 16, 0, 0);
}

// fp32 -> (hi, lo) f16 split: hi+lo represents x to ~2^-22
__device__ __forceinline__ void splitH4(float4 v, ushort4& h, ushort4& l) {
  h.x = f2h(v.x); l.x = f2h(v.x - h2f(h.x));
  h.y = f2h(v.y); l.y = f2h(v.y - h2f(h.y));
  h.z = f2h(v.z); l.z = f2h(v.z - h2f(h.z));
  h.w = f2h(v.w); l.w = f2h(v.w - h2f(h.w));
}

// ------------- fused prep: x f16-split + f16-transpose | W casts | W2 cast ----------
__global__ __launch_bounds__(256) void prep_all(const float* __restrict__ x,
                                                const float* __restrict__ Wq,
                                                const float* __restrict__ Wk,
                                                const float* __restrict__ W2,
                                                u16* __restrict__ xh, u16* __restrict__ xl,
                                                u16* __restrict__ Wf, u16* __restrict__ W2f,
                                                u16* __restrict__ XT) {
  __shared__ float tile[64][65];
  int b = blockIdx.x;
  int t = threadIdx.x;
  if (b < 2048) {
    int mb = (b >> 5) * 64, db = (b & 31) * 64;
    int tx = t & 15, ty = t >> 4;
#pragma unroll
    for (int rr = 0; rr < 4; ++rr) {
      int row = rr * 16 + ty;
      float4 v = *(const float4*)(x + (size_t)(mb + row) * DMODEL + db + tx * 4);
      ushort4 h, l; splitH4(v, h, l);
      size_t gi = ((size_t)(mb + row) * DMODEL + db) / 4 + tx;
      ((ushort4*)xh)[gi] = h; ((ushort4*)xl)[gi] = l;
      tile[row][tx * 4 + 0] = v.x; tile[row][tx * 4 + 1] = v.y;
      tile[row][tx * 4 + 2] = v.z; tile[row][tx * 4 + 3] = v.w;
    }
    __syncthreads();
#pragma unroll
    for (int rr = 0; rr < 4; ++rr) {
      int r = (t >> 4) * 4 + rr;
      int c0 = (t & 15) * 4;
      ushort4 o;
      o.x = f2h(tile[c0 + 0][r]); o.y = f2h(tile[c0 + 1][r]);
      o.z = f2h(tile[c0 + 2][r]); o.w = f2h(tile[c0 + 3][r]);
      *(ushort4*)(XT + (size_t)(db + r) * NCTX + mb + c0) = o;
    }
  } else if (b < 2560) {               // cast Wq | Wk (single f16)
    int wk = (b >= 2304);
    int i = (b - (wk ? 2304 : 2048)) * 256 + t;
    const float* W = wk ? Wk : Wq;
    size_t off = wk ? ((size_t)DHEAD * DMODEL / 4) : 0;
    float4 v = ((const float4*)W)[i];
    ushort4 o;
    o.x = f2h(v.x); o.y = f2h(v.y); o.z = f2h(v.z); o.w = f2h(v.w);
    ((ushort4*)Wf)[off + i] = o;
  } else {                             // cast W2
    int i = (b - 2560) * 256 + t;
    float4 v = ((const float4*)W2)[i];
    ushort4 o;
    o.x = f2h(v.x); o.y = f2h(v.y); o.z = f2h(v.z); o.w = f2h(v.w);
    ((ushort4*)W2f)[i] = o;
  }
}

// ---------------- 8-way split-K reduce (fp32 in) -> f16 ----------------
__global__ __launch_bounds__(256) void reduce8_f16(const float* __restrict__ P,
                                                   u16* __restrict__ out, int n4) {
  int i = blockIdx.x * 256 + threadIdx.x;
  if (i >= n4) return;
  float4 s = ((const float4*)P)[i];
#pragma unroll
  for (int z = 1; z < 8; ++z) {
    float4 v = ((const float4*)P)[(size_t)z * n4 + i];
    s.x += v.x; s.y += v.y; s.z += v.z; s.w += v.w;
  }
  ushort4 o;
  o.x = f2h(s.x); o.y = f2h(s.y); o.z = f2h(s.z); o.w = f2h(s.w);
  ((ushort4*)out)[i] = o;
}

// ---------------- causal 4-chunk f16 split-K reduce -> f16 ----------------
// one block per row; chunk c active iff c*1024 < (bm+1)*128  <=>  c <= row>>10
__global__ __launch_bounds__(256) void reduce_c4(const u16* __restrict__ P,
                                                 u16* __restrict__ out, size_t cs) {
  int row = blockIdx.x;
  int t = threadIdx.x;
  int nc = (row >> 10) + 1;
  size_t base = (size_t)row * DMODEL + t * 8;
  float s[8] = {};
  for (int c = 0; c < nc; ++c) {
    u16x8 v = *(const u16x8*)(P + (size_t)c * cs + base);
#pragma unroll
    for (int k = 0; k < 8; ++k) s[k] += h2f(v[k]);
  }
  u16x8 o;
#pragma unroll
  for (int k = 0; k < 8; ++k) o[k] = f2h(s[k]);
  *(u16x8*)(out + base) = o;
}

// ---------------- 2-way f16 split-K reduce -> fp32 (final output) ----------------
__global__ __launch_bounds__(256) void reduce2_hf(const u16* __restrict__ P0,
                                                  const u16* __restrict__ P1,
                                                  float* __restrict__ out, int n8) {
  int i = blockIdx.x * 256 + threadIdx.x;
  if (i >= n8) return;
  u16x8 a = ((const u16x8*)P0)[i];
  u16x8 b = ((const u16x8*)P1)[i];
  float4 o0, o1;
  o0.x = h2f(a[0]) + h2f(b[0]); o0.y = h2f(a[1]) + h2f(b[1]);
  o0.z = h2f(a[2]) + h2f(b[2]); o0.w = h2f(a[3]) + h2f(b[3]);
  o1.x = h2f(a[4]) + h2f(b[4]); o1.y = h2f(a[5]) + h2f(b[5]);
  o1.z = h2f(a[6]) + h2f(b[6]); o1.w = h2f(a[7]) + h2f(b[7]);
  ((float4*)out)[i * 2 + 0] = o0;
  ((float4*)out)[i * 2 + 1] = o1;
}

// ---------------- row softmax (fp32) -> f16 attn ----------------
__global__ __launch_bounds__(256) void softmax_rows(const float* __restrict__ S,
                                                    u16* __restrict__ P) {
  int i = blockIdx.x;
  int t = threadIdx.x;
  __shared__ float rowbuf[NCTX];
  __shared__ float red[4];
  __shared__ float red2[4];
  const float* srow = S + (size_t)i * NCTX;
  int len = i + 1;
  int jmax = ((i >> 7) + 1) << 7;  // causal gemm reads j < 128*(bm+1)
  float mx = -3.0e38f;
  for (int j = t * 4; j < len; j += 1024) {
    if (j + 4 <= len) {
      float4 v = *(const float4*)(srow + j);
      *(float4*)(rowbuf + j) = v;
      mx = fmaxf(mx, fmaxf(fmaxf(v.x, v.y), fmaxf(v.z, v.w)));
    } else {
      for (int k = j; k < len; ++k) {
        float v = srow[k];
        rowbuf[k] = v;
        mx = fmaxf(mx, v);
      }
    }
  }
#pragma unroll
  for (int o = 32; o > 0; o >>= 1) mx = fmaxf(mx, __shfl_xor(mx, o, 64));
  if ((t & 63) == 0) red[t >> 6] = mx;
  __syncthreads();
  mx = fmaxf(fmaxf(red[0], red[1]), fmaxf(red[2], red[3]));
  float sum = 0.f;
  for (int j = t; j < len; j += 256) {
    float e = __expf(rowbuf[j] - mx);
    rowbuf[j] = e;
    sum += e;
  }
#pragma unroll
  for (int o = 32; o > 0; o >>= 1) sum += __shfl_xor(sum, o, 64);
  if ((t & 63) == 0) red2[t >> 6] = sum;
  __syncthreads();
  float inv = 1.0f / (red2[0] + red2[1] + red2[2] + red2[3]);
  u16* prow = P + (size_t)i * NCTX;
  for (int j = t * 4; j < jmax; j += 1024) {
    ushort4 o;
    o.x = (j + 0 < len) ? f2h(rowbuf[j + 0] * inv) : (u16)0;
    o.y = (j + 1 < len) ? f2h(rowbuf[j + 1] * inv) : (u16)0;
    o.z = (j + 2 < len) ? f2h(rowbuf[j + 2] * inv) : (u16)0;
    o.w = (j + 3 < len) ? f2h(rowbuf[j + 3] * inv) : (u16)0;
    *(ushort4*)(prow + j) = o;
  }
}

// ---------------- f16 MFMA GEMM, B^T, 128x128, BK=64, XOR swizzle, fp32 out -------
// used for scores only (tri=1): skip tiles with bn > bm, direct fp32 store.
__global__ __launch_bounds__(256, 4) void gemm_f16_p(const u16* __restrict__ A,
                                                     const u16* __restrict__ B,
                                                     float* __restrict__ C,
                                                     int lda, int ldb, int ldc,
                                                     int K, int KC, size_t chunkStride,
                                                     int causal, int tri) {
  int bm = gridDim.x - 1 - blockIdx.x, bn = blockIdx.y, kc = blockIdx.z;
  if (tri && bn > bm) return;
  int kEnd = K;
  if (causal) { int ke = (bm + 1) * 128; if (ke < kEnd) kEnd = ke; }
  int kStart = kc * KC;
  if (kStart >= kEnd) return;
  int kStop = kStart + KC < kEnd ? kStart + KC : kEnd;
  __shared__ __align__(16) u16 As[128 * 64];
  __shared__ __align__(16) u16 Bs[128 * 64];
  int t = threadIdx.x;
  int lane = t & 63, w = t >> 6;
  int m0 = bm * 128, n0 = bn * 128;
  int wm = (w >> 1) * 64, wn = (w & 1) * 64;
  int mfrag = lane & 15, quad = lane >> 4;
  int srow = t >> 3, schunk = t & 7;
  int rsw = mfrag & 7;
  f32x4 acc[4][4] = {};
  for (int kt = kStart; kt < kStop; kt += 64) {
#pragma unroll
    for (int p = 0; p < 4; ++p) {
      int row = p * 32 + srow;
      int gsc = schunk ^ (row & 7);
      gl_lds16(A + (size_t)(m0 + row) * lda + kt + gsc * 8, As + (size_t)(p * 256 + t) * 8);
      gl_lds16(B + (size_t)(n0 + row) * ldb + kt + gsc * 8, Bs + (size_t)(p * 256 + t) * 8);
    }
    __syncthreads();
#pragma unroll
    for (int ks = 0; ks < 2; ++ks) {
      int c0 = ((ks * 4 + quad) ^ rsw) * 8;
      f16x8 af[4], bfr[4];
#pragma unroll
      for (int i = 0; i < 4; ++i)
        af[i] = *(const f16x8*)(As + (wm + i * 16 + mfrag) * 64 + c0);
#pragma unroll
      for (int j = 0; j < 4; ++j)
        bfr[j] = *(const f16x8*)(Bs + (wn + j * 16 + mfrag) * 64 + c0);
#pragma unroll
      for (int i = 0; i < 4; ++i)
#pragma unroll
        for (int j = 0; j < 4; ++j)
          acc[i][j] = __builtin_amdgcn_mfma_f32_16x16x32_f16(af[i], bfr[j], acc[i][j], 0, 0, 0);
    }
    __syncthreads();
  }
  float* Cc = C + (size_t)kc * chunkStride;
#pragma unroll
  for (int i = 0; i < 4; ++i)
#pragma unroll
    for (int j = 0; j < 4; ++j)
#pragma unroll
      for (int rr = 0; rr < 4; ++rr) {
        int row = m0 + wm + i * 16 + quad * 4 + rr;
        int col = n0 + wn + j * 16 + mfrag;
        Cc[(size_t)row * ldc + col] = acc[i][j][rr];
      }
}

// ---------------- same GEMM core, f16 split-K partial output ----------------
// attn@x (causal=1, z=4, KC=1024) and out@W2 (causal=0, z=2, KC=1024).
__global__ __launch_bounds__(256, 4) void gemm_f16_h(const u16* __restrict__ A,
                                                     const u16* __restrict__ B,
                                                     u16* __restrict__ C,
                                                     int lda, int ldb, int ldc,
                                                     int K, int KC, size_t chunkStride,
                                                     int causal) {
  int bm = gridDim.x - 1 - blockIdx.x, bn = blockIdx.y, kc = blockIdx.z;
  int kEnd = K;
  if (causal) { int ke = (bm + 1) * 128; if (ke < kEnd) kEnd = ke; }
  int kStart = kc * KC;
  if (kStart >= kEnd) return;
  int kStop = kStart + KC < kEnd ? kStart + KC : kEnd;
  __shared__ __align__(16) u16 As[128 * 64];
  __shared__ __align__(16) u16 Bs[128 * 64];
  int t = threadIdx.x;
  int lane = t & 63, w = t >> 6;
  int m0 = bm * 128, n0 = bn * 128;
  int wm = (w >> 1) * 64, wn = (w & 1) * 64;
  int mfrag = lane & 15, quad = lane >> 4;
  int srow = t >> 3, schunk = t & 7;
  int rsw = mfrag & 7;
  f32x4 acc[4][4] = {};
  for (int kt = kStart; kt < kStop; kt += 64) {
#pragma unroll
    for (int p = 0; p < 4; ++p) {
      int row = p * 32 + srow;
      int gsc = schunk ^ (row & 7);
      gl_lds16(A + (size_t)(m0 + row) * lda + kt + gsc * 8, As + (size_t)(p * 256 + t) * 8);
      gl_lds16(B + (size_t)(n0 + row) * ldb + kt + gsc * 8, Bs + (size_t)(p * 256 + t) * 8);
    }
    __syncthreads();
#pragma unroll
    for (int ks = 0; ks < 2; ++ks) {
      int c0 = ((ks * 4 + quad) ^ rsw) * 8;
      f16x8 af[4], bfr[4];
#pragma unroll
      for (int i = 0; i < 4; ++i)
        af[i] = *(const f16x8*)(As + (wm + i * 16 + mfrag) * 64 + c0);
#pragma unroll
      for (int j = 0; j < 4; ++j)
        bfr[j] = *(const f16x8*)(Bs + (wn + j * 16 + mfrag) * 64 + c0);
#pragma unroll
      for (int i = 0; i < 4; ++i)
#pragma unroll
        for (int j = 0; j < 4; ++j)
          acc[i][j] = __builtin_amdgcn_mfma_f32_16x16x32_f16(af[i], bfr[j], acc[i][j], 0, 0, 0);
    }
    __syncthreads();
  }
  u16* Cc = C + (size_t)kc * chunkStride;
#pragma unroll
  for (int i = 0; i < 4; ++i)
#pragma unroll
    for (int j = 0; j < 4; ++j)
#pragma unroll
      for (int rr = 0; rr < 4; ++rr) {
        int row = m0 + wm + i * 16 + quad * 4 + rr;
        int col = n0 + wn + j * 16 + mfrag;
        Cc[(size_t)row * ldc + col] = f2h(acc[i][j][rr]);
      }
}

// ---------------- f16x2 split-A MFMA GEMM (qk projection) -------------------------
__global__ __launch_bounds__(256, 3) void gemm_f16x2_p(const u16* __restrict__ Ah,
                                                       const u16* __restrict__ Al,
                                                       const u16* __restrict__ B,
                                                       float* __restrict__ C,
                                                       int lda, int ldb, int ldc,
                                                       int K, int KC, size_t chunkStride) {
  int bm = blockIdx.x, bn = blockIdx.y, kc = blockIdx.z;
  int kStart = kc * KC;
  int kStop = kStart + KC < K ? kStart + KC : K;
  __shared__ __align__(16) u16 Ash[128 * 64];
  __shared__ __align__(16) u16 Asl[128 * 64];
  __shared__ __align__(16) u16 Bs[128 * 64];
  int t = threadIdx.x;
  int lane = t & 63, w = t >> 6;
  int m0 = bm * 128, n0 = bn * 128;
  int wm = (w >> 1) * 64, wn = (w & 1) * 64;
  int mfrag = lane & 15, quad = lane >> 4;
  int srow = t >> 3, schunk = t & 7;
  int rsw = mfrag & 7;
  f32x4 acc[4][4] = {};
  for (int kt = kStart; kt < kStop; kt += 64) {
#pragma unroll
    for (int p = 0; p < 4; ++p) {
      int row = p * 32 + srow;
      int gsc = schunk ^ (row & 7);
      size_t aoff = (size_t)(m0 + row) * lda + kt + gsc * 8;
      size_t loff = (size_t)(p * 256 + t) * 8;
      gl_lds16(Ah + aoff, Ash + loff);
      gl_lds16(Al + aoff, Asl + loff);
      gl_lds16(B + (size_t)(n0 + row) * ldb + kt + gsc * 8, Bs + loff);
    }
    __syncthreads();
#pragma unroll
    for (int ks = 0; ks < 2; ++ks) {
      int c0 = ((ks * 4 + quad) ^ rsw) * 8;
      f16x8 a0[4], bfr[4];
#pragma unroll
      for (int j = 0; j < 4; ++j)
        bfr[j] = *(const f16x8*)(Bs + (wn + j * 16 + mfrag) * 64 + c0);
#pragma unroll
      for (int i = 0; i < 4; ++i)
        a0[i] = *(const f16x8*)(Ash + (wm + i * 16 + mfrag) * 64 + c0);
#pragma unroll
      for (int i = 0; i < 4; ++i)
#pragma unroll
        for (int j = 0; j < 4; ++j)
          acc[i][j] = __builtin_amdgcn_mfma_f32_16x16x32_f16(a0[i], bfr[j], acc[i][j], 0, 0, 0);
#pragma unroll
      for (int i = 0; i < 4; ++i)
        a0[i] = *(const f16x8*)(Asl + (wm + i * 16 + mfrag) * 64 + c0);
#pragma unroll
      for (int i = 0; i < 4; ++i)
#pragma unroll
        for (int j = 0; j < 4; ++j)
          acc[i][j] = __builtin_amdgcn_mfma_f32_16x16x32_f16(a0[i], bfr[j], acc[i][j], 0, 0, 0);
    }
    __syncthreads();
  }
  float* Cc = C + (size_t)kc * chunkStride;
#pragma unroll
  for (int i = 0; i < 4; ++i)
#pragma unroll
    for (int j = 0; j < 4; ++j)
#pragma unroll
      for (int rr = 0; rr < 4; ++rr) {
        int row = m0 + wm + i * 16 + quad * 4 + rr;
        int col = n0 + wn + j * 16 + mfrag;
        Cc[(size_t)row * ldc + col] = acc[i][j][rr];
      }
}

extern "C" void kernel_launch(void* const* d_in, const int* in_sizes, int n_in,
                              void* d_out, int out_size, void* d_ws, size_t ws_size,
                              hipStream_t stream) {
  const float* x  = (const float*)d_in[0];
  const float* Wk = (const float*)d_in[1];
  const float* Wq = (const float*)d_in[2];
  const float* W2 = (const float*)d_in[3];

  char* ws = (char*)d_ws;
  const size_t MB = 1024 * 1024;
  // persistent region [0, 75 MB)
  u16*   QKf  = (u16*)  (ws + 0);            //  2 MB  [4096,256] f16 (q | k)
  u16*   Wf   = (u16*)  (ws + 2 * MB);       //  1 MB  [256,2048] (Wq ; Wk) f16
  u16*   xT   = (u16*)  (ws + 3 * MB);       // 16 MB  [2048,4096] f16
  u16*   W2f  = (u16*)  (ws + 19 * MB);      //  8 MB  [2048,2048] f16
  u16*   outb = (u16*)  (ws + 27 * MB);      // 16 MB  [4096,2048] f16
  u16*   attn = (u16*)  (ws + 43 * MB);      // 32 MB  [4096,4096] f16
  // reusable region A [75, 139 MB) — lifetimes strictly sequential:
  u16*   xh   = (u16*)  (ws + 75 * MB);      // 16 MB  (dead after qk gemm)
  u16*   xl   = (u16*)  (ws + 91 * MB);      // 16 MB  (dead after qk gemm)
  float* QKp  = (float*)(ws + 107 * MB);     // 32 MB  8 x [4096,256] partials
  float* S    = (float*)(ws + 75 * MB);      // 64 MB  scores (after xh/xl/QKp dead)
  u16*   Ph   = (u16*)  (ws + 75 * MB);      // 64 MB  4 x [4096,2048] f16 partials (after S dead)

  const int XN8 = NCTX * DMODEL / 8;
  const int QKN4 = NCTX * 256 / 4;
  const size_t CS = (size_t)NCTX * DMODEL;   // partial chunk stride (elements)

  // fused prep: x f16-split + f16 transpose + W/W2 casts
  prep_all<<<6656, 256, 0, stream>>>(x, Wq, Wk, W2, xh, xl, Wf, W2f, xT);

  // q,k = (xh+xl) @ [Wq;Wk]^T  (f16x2 2-pass), split-K KC=256 -> 512 blocks
  gemm_f16x2_p<<<dim3(NCTX / 128, 2, 8), 256, 0, stream>>>(
      xh, xl, Wf, QKp, DMODEL, DMODEL, 256, DMODEL, 256, (size_t)NCTX * 256);
  reduce8_f16<<<(QKN4 + 255) / 256, 256, 0, stream>>>(QKp, QKf, QKN4);

  // scores = q @ k^T, single-pass f16, lower-triangular tiles, direct fp32 store
  gemm_f16_p<<<dim3(NCTX / 128, NCTX / 128, 1), 256, 0, stream>>>(
      QKf, QKf + DHEAD, S, 256, 256, NCTX, DHEAD, DHEAD, 0, 0, 1);
  softmax_rows<<<NCTX, 256, 0, stream>>>(S, attn);

  // out = attn @ x (causal): z=4, KC=1024, f16 partials for balance + traffic
  gemm_f16_h<<<dim3(NCTX / 128, DMODEL / 128, 4), 256, 0, stream>>>(
      attn, xT, Ph, NCTX, NCTX, DMODEL, NCTX, 1024, CS, 1);
  reduce_c4<<<NCTX, 256, 0, stream>>>(Ph, outb, CS);

  // final = out @ W2^T: z=2, KC=1024, f16 partials
  gemm_f16_h<<<dim3(NCTX / 128, DMODEL / 128, 2), 256, 0, stream>>>(
      outb, W2f, Ph, DMODEL, DMODEL, DMODEL, DMODEL, 1024, CS, 0);
  reduce2_hf<<<(XN8 + 255) / 256, 256, 0, stream>>>(Ph, Ph + CS, (float*)d_out, XN8);
}

// Round 3
// 256.819 us; speedup vs baseline: 1.0568x; 1.0568x over previous
//
#include <hip/hip_runtime.h>

#define NCTX 4096
#define DMODEL 2048
#define DHEAD 128

typedef _Float16 f16;
typedef f16 f16x8 __attribute__((ext_vector_type(8)));
typedef float f32x4 __attribute__((ext_vector_type(4)));
typedef unsigned short u16;
typedef u16 u16x8 __attribute__((ext_vector_type(8)));

__device__ __forceinline__ u16 f2h(float f) {
  union { f16 h; u16 u; } v; v.h = (f16)f; return v.u;
}
__device__ __forceinline__ float h2f(u16 u) {
  union { u16 u; f16 h; } v; v.u = u; return (float)v.h;
}

__device__ __forceinline__ void gl_lds16(const void* g, void* l) {
  __builtin_amdgcn_global_load_lds((const __attribute__((address_space(1))) void*)g,
                                   (__attribute__((address_space(3))) void*)l, 16, 0, 0);
}

// fp32 -> (hi, lo) f16 split: hi+lo represents x to ~2^-22
__device__ __forceinline__ void splitH4(float4 v, ushort4& h, ushort4& l) {
  h.x = f2h(v.x); l.x = f2h(v.x - h2f(h.x));
  h.y = f2h(v.y); l.y = f2h(v.y - h2f(h.y));
  h.z = f2h(v.z); l.z = f2h(v.z - h2f(h.z));
  h.w = f2h(v.w); l.w = f2h(v.w - h2f(h.w));
}

// ------------- fused prep: x f16-split + f16-transpose | W casts | W2 cast ----------
__global__ __launch_bounds__(256) void prep_all(const float* __restrict__ x,
                                                const float* __restrict__ Wq,
                                                const float* __restrict__ Wk,
                                                const float* __restrict__ W2,
                                                u16* __restrict__ xh, u16* __restrict__ xl,
                                                u16* __restrict__ Wf, u16* __restrict__ W2f,
                                                u16* __restrict__ XT) {
  __shared__ float tile[64][65];
  int b = blockIdx.x;
  int t = threadIdx.x;
  if (b < 2048) {
    int mb = (b >> 5) * 64, db = (b & 31) * 64;
    int tx = t & 15, ty = t >> 4;
#pragma unroll
    for (int rr = 0; rr < 4; ++rr) {
      int row = rr * 16 + ty;
      float4 v = *(const float4*)(x + (size_t)(mb + row) * DMODEL + db + tx * 4);
      ushort4 h, l; splitH4(v, h, l);
      size_t gi = ((size_t)(mb + row) * DMODEL + db) / 4 + tx;
      ((ushort4*)xh)[gi] = h; ((ushort4*)xl)[gi] = l;
      tile[row][tx * 4 + 0] = v.x; tile[row][tx * 4 + 1] = v.y;
      tile[row][tx * 4 + 2] = v.z; tile[row][tx * 4 + 3] = v.w;
    }
    __syncthreads();
#pragma unroll
    for (int rr = 0; rr < 4; ++rr) {
      int r = (t >> 4) * 4 + rr;
      int c0 = (t & 15) * 4;
      ushort4 o;
      o.x = f2h(tile[c0 + 0][r]); o.y = f2h(tile[c0 + 1][r]);
      o.z = f2h(tile[c0 + 2][r]); o.w = f2h(tile[c0 + 3][r]);
      *(ushort4*)(XT + (size_t)(db + r) * NCTX + mb + c0) = o;
    }
  } else if (b < 2560) {               // cast Wq | Wk (single f16)
    int wk = (b >= 2304);
    int i = (b - (wk ? 2304 : 2048)) * 256 + t;
    const float* W = wk ? Wk : Wq;
    size_t off = wk ? ((size_t)DHEAD * DMODEL / 4) : 0;
    float4 v = ((const float4*)W)[i];
    ushort4 o;
    o.x = f2h(v.x); o.y = f2h(v.y); o.z = f2h(v.z); o.w = f2h(v.w);
    ((ushort4*)Wf)[off + i] = o;
  } else {                             // cast W2
    int i = (b - 2560) * 256 + t;
    float4 v = ((const float4*)W2)[i];
    ushort4 o;
    o.x = f2h(v.x); o.y = f2h(v.y); o.z = f2h(v.z); o.w = f2h(v.w);
    ((ushort4*)W2f)[i] = o;
  }
}

// ---------------- 8-way split-K reduce (fp32 in) -> f16 ----------------
__global__ __launch_bounds__(256) void reduce8_f16(const float* __restrict__ P,
                                                   u16* __restrict__ out, int n4) {
  int i = blockIdx.x * 256 + threadIdx.x;
  if (i >= n4) return;
  float4 s = ((const float4*)P)[i];
#pragma unroll
  for (int z = 1; z < 8; ++z) {
    float4 v = ((const float4*)P)[(size_t)z * n4 + i];
    s.x += v.x; s.y += v.y; s.z += v.z; s.w += v.w;
  }
  ushort4 o;
  o.x = f2h(s.x); o.y = f2h(s.y); o.z = f2h(s.z); o.w = f2h(s.w);
  ((ushort4*)out)[i] = o;
}

// ---------------- causal 2-chunk f16 split-K reduce (rows >= 2048 only) ----------
// rows < 2048 were written final-direct by the gemm (chunk covers whole causal K).
__global__ __launch_bounds__(256) void reduce_c2(const u16* __restrict__ P,
                                                 u16* __restrict__ out, size_t cs) {
  int row = 2048 + blockIdx.x;
  int t = threadIdx.x;
  size_t base = (size_t)row * DMODEL + t * 8;
  u16x8 a = *(const u16x8*)(P + base);
  u16x8 b = *(const u16x8*)(P + cs + base);
  u16x8 o;
#pragma unroll
  for (int k = 0; k < 8; ++k) o[k] = f2h(h2f(a[k]) + h2f(b[k]));
  *(u16x8*)(out + base) = o;
}

// ---------------- row softmax (fp32) -> f16 attn ----------------
__global__ __launch_bounds__(256) void softmax_rows(const float* __restrict__ S,
                                                    u16* __restrict__ P) {
  int i = blockIdx.x;
  int t = threadIdx.x;
  __shared__ float rowbuf[NCTX];
  __shared__ float red[4];
  __shared__ float red2[4];
  const float* srow = S + (size_t)i * NCTX;
  int len = i + 1;
  int jmax = ((i >> 7) + 1) << 7;  // causal gemm reads j < 128*(bm+1)
  float mx = -3.0e38f;
  for (int j = t * 4; j < len; j += 1024) {
    if (j + 4 <= len) {
      float4 v = *(const float4*)(srow + j);
      *(float4*)(rowbuf + j) = v;
      mx = fmaxf(mx, fmaxf(fmaxf(v.x, v.y), fmaxf(v.z, v.w)));
    } else {
      for (int k = j; k < len; ++k) {
        float v = srow[k];
        rowbuf[k] = v;
        mx = fmaxf(mx, v);
      }
    }
  }
#pragma unroll
  for (int o = 32; o > 0; o >>= 1) mx = fmaxf(mx, __shfl_xor(mx, o, 64));
  if ((t & 63) == 0) red[t >> 6] = mx;
  __syncthreads();
  mx = fmaxf(fmaxf(red[0], red[1]), fmaxf(red[2], red[3]));
  float sum = 0.f;
  for (int j = t; j < len; j += 256) {
    float e = __expf(rowbuf[j] - mx);
    rowbuf[j] = e;
    sum += e;
  }
#pragma unroll
  for (int o = 32; o > 0; o >>= 1) sum += __shfl_xor(sum, o, 64);
  if ((t & 63) == 0) red2[t >> 6] = sum;
  __syncthreads();
  float inv = 1.0f / (red2[0] + red2[1] + red2[2] + red2[3]);
  u16* prow = P + (size_t)i * NCTX;
  for (int j = t * 4; j < jmax; j += 1024) {
    ushort4 o;
    o.x = (j + 0 < len) ? f2h(rowbuf[j + 0] * inv) : (u16)0;
    o.y = (j + 1 < len) ? f2h(rowbuf[j + 1] * inv) : (u16)0;
    o.z = (j + 2 < len) ? f2h(rowbuf[j + 2] * inv) : (u16)0;
    o.w = (j + 3 < len) ? f2h(rowbuf[j + 3] * inv) : (u16)0;
    *(ushort4*)(prow + j) = o;
  }
}

// ---------------- f16 MFMA GEMM, B^T, 128x128, BK=64, XOR swizzle, fp32 out -------
// scores (tri=1, skip bn>bm tiles) and out@W2 (z=1 direct fp32 store to d_out).
__global__ __launch_bounds__(256, 4) void gemm_f16_p(const u16* __restrict__ A,
                                                     const u16* __restrict__ B,
                                                     float* __restrict__ C,
                                                     int lda, int ldb, int ldc,
                                                     int K, int KC, size_t chunkStride,
                                                     int causal, int tri) {
  int bm = gridDim.x - 1 - blockIdx.x, bn = blockIdx.y, kc = blockIdx.z;
  if (tri && bn > bm) return;
  int kEnd = K;
  if (causal) { int ke = (bm + 1) * 128; if (ke < kEnd) kEnd = ke; }
  int kStart = kc * KC;
  if (kStart >= kEnd) return;
  int kStop = kStart + KC < kEnd ? kStart + KC : kEnd;
  __shared__ __align__(16) u16 As[128 * 64];
  __shared__ __align__(16) u16 Bs[128 * 64];
  int t = threadIdx.x;
  int lane = t & 63, w = t >> 6;
  int m0 = bm * 128, n0 = bn * 128;
  int wm = (w >> 1) * 64, wn = (w & 1) * 64;
  int mfrag = lane & 15, quad = lane >> 4;
  int srow = t >> 3, schunk = t & 7;
  int rsw = mfrag & 7;
  f32x4 acc[4][4] = {};
  for (int kt = kStart; kt < kStop; kt += 64) {
#pragma unroll
    for (int p = 0; p < 4; ++p) {
      int row = p * 32 + srow;
      int gsc = schunk ^ (row & 7);
      gl_lds16(A + (size_t)(m0 + row) * lda + kt + gsc * 8, As + (size_t)(p * 256 + t) * 8);
      gl_lds16(B + (size_t)(n0 + row) * ldb + kt + gsc * 8, Bs + (size_t)(p * 256 + t) * 8);
    }
    __syncthreads();
#pragma unroll
    for (int ks = 0; ks < 2; ++ks) {
      int c0 = ((ks * 4 + quad) ^ rsw) * 8;
      f16x8 af[4], bfr[4];
#pragma unroll
      for (int i = 0; i < 4; ++i)
        af[i] = *(const f16x8*)(As + (wm + i * 16 + mfrag) * 64 + c0);
#pragma unroll
      for (int j = 0; j < 4; ++j)
        bfr[j] = *(const f16x8*)(Bs + (wn + j * 16 + mfrag) * 64 + c0);
#pragma unroll
      for (int i = 0; i < 4; ++i)
#pragma unroll
        for (int j = 0; j < 4; ++j)
          acc[i][j] = __builtin_amdgcn_mfma_f32_16x16x32_f16(af[i], bfr[j], acc[i][j], 0, 0, 0);
    }
    __syncthreads();
  }
  float* Cc = C + (size_t)kc * chunkStride;
#pragma unroll
  for (int i = 0; i < 4; ++i)
#pragma unroll
    for (int j = 0; j < 4; ++j)
#pragma unroll
      for (int rr = 0; rr < 4; ++rr) {
        int row = m0 + wm + i * 16 + quad * 4 + rr;
        int col = n0 + wn + j * 16 + mfrag;
        Cc[(size_t)row * ldc + col] = acc[i][j][rr];
      }
}

// ---------------- same GEMM core, f16 out: split-K partial OR final-direct --------
// attn@x (causal=1, z=2, KC=2048). Blocks whose chunk covers the whole causal K
// (kStart==0 && kStop==kEnd, i.e. rows < 2048) store straight to Cf (outb);
// others store f16 partials to C + kc*chunkStride for reduce_c2.
__global__ __launch_bounds__(256, 4) void gemm_f16_h(const u16* __restrict__ A,
                                                     const u16* __restrict__ B,
                                                     u16* __restrict__ C,
                                                     u16* __restrict__ Cf,
                                                     int lda, int ldb, int ldc,
                                                     int K, int KC, size_t chunkStride,
                                                     int causal) {
  int bm = gridDim.x - 1 - blockIdx.x, bn = blockIdx.y, kc = blockIdx.z;
  int kEnd = K;
  if (causal) { int ke = (bm + 1) * 128; if (ke < kEnd) kEnd = ke; }
  int kStart = kc * KC;
  if (kStart >= kEnd) return;
  int kStop = kStart + KC < kEnd ? kStart + KC : kEnd;
  __shared__ __align__(16) u16 As[128 * 64];
  __shared__ __align__(16) u16 Bs[128 * 64];
  int t = threadIdx.x;
  int lane = t & 63, w = t >> 6;
  int m0 = bm * 128, n0 = bn * 128;
  int wm = (w >> 1) * 64, wn = (w & 1) * 64;
  int mfrag = lane & 15, quad = lane >> 4;
  int srow = t >> 3, schunk = t & 7;
  int rsw = mfrag & 7;
  f32x4 acc[4][4] = {};
  for (int kt = kStart; kt < kStop; kt += 64) {
#pragma unroll
    for (int p = 0; p < 4; ++p) {
      int row = p * 32 + srow;
      int gsc = schunk ^ (row & 7);
      gl_lds16(A + (size_t)(m0 + row) * lda + kt + gsc * 8, As + (size_t)(p * 256 + t) * 8);
      gl_lds16(B + (size_t)(n0 + row) * ldb + kt + gsc * 8, Bs + (size_t)(p * 256 + t) * 8);
    }
    __syncthreads();
#pragma unroll
    for (int ks = 0; ks < 2; ++ks) {
      int c0 = ((ks * 4 + quad) ^ rsw) * 8;
      f16x8 af[4], bfr[4];
#pragma unroll
      for (int i = 0; i < 4; ++i)
        af[i] = *(const f16x8*)(As + (wm + i * 16 + mfrag) * 64 + c0);
#pragma unroll
      for (int j = 0; j < 4; ++j)
        bfr[j] = *(const f16x8*)(Bs + (wn + j * 16 + mfrag) * 64 + c0);
#pragma unroll
      for (int i = 0; i < 4; ++i)
#pragma unroll
        for (int j = 0; j < 4; ++j)
          acc[i][j] = __builtin_amdgcn_mfma_f32_16x16x32_f16(af[i], bfr[j], acc[i][j], 0, 0, 0);
    }
    __syncthreads();
  }
  u16* Cc = (kStart == 0 && kStop == kEnd) ? Cf : (C + (size_t)kc * chunkStride);
#pragma unroll
  for (int i = 0; i < 4; ++i)
#pragma unroll
    for (int j = 0; j < 4; ++j)
#pragma unroll
      for (int rr = 0; rr < 4; ++rr) {
        int row = m0 + wm + i * 16 + quad * 4 + rr;
        int col = n0 + wn + j * 16 + mfrag;
        Cc[(size_t)row * ldc + col] = f2h(acc[i][j][rr]);
      }
}

// ---------------- f16x2 split-A MFMA GEMM (qk projection) -------------------------
__global__ __launch_bounds__(256, 3) void gemm_f16x2_p(const u16* __restrict__ Ah,
                                                       const u16* __restrict__ Al,
                                                       const u16* __restrict__ B,
                                                       float* __restrict__ C,
                                                       int lda, int ldb, int ldc,
                                                       int K, int KC, size_t chunkStride) {
  int bm = blockIdx.x, bn = blockIdx.y, kc = blockIdx.z;
  int kStart = kc * KC;
  int kStop = kStart + KC < K ? kStart + KC : K;
  __shared__ __align__(16) u16 Ash[128 * 64];
  __shared__ __align__(16) u16 Asl[128 * 64];
  __shared__ __align__(16) u16 Bs[128 * 64];
  int t = threadIdx.x;
  int lane = t & 63, w = t >> 6;
  int m0 = bm * 128, n0 = bn * 128;
  int wm = (w >> 1) * 64, wn = (w & 1) * 64;
  int mfrag = lane & 15, quad = lane >> 4;
  int srow = t >> 3, schunk = t & 7;
  int rsw = mfrag & 7;
  f32x4 acc[4][4] = {};
  for (int kt = kStart; kt < kStop; kt += 64) {
#pragma unroll
    for (int p = 0; p < 4; ++p) {
      int row = p * 32 + srow;
      int gsc = schunk ^ (row & 7);
      size_t aoff = (size_t)(m0 + row) * lda + kt + gsc * 8;
      size_t loff = (size_t)(p * 256 + t) * 8;
      gl_lds16(Ah + aoff, Ash + loff);
      gl_lds16(Al + aoff, Asl + loff);
      gl_lds16(B + (size_t)(n0 + row) * ldb + kt + gsc * 8, Bs + loff);
    }
    __syncthreads();
#pragma unroll
    for (int ks = 0; ks < 2; ++ks) {
      int c0 = ((ks * 4 + quad) ^ rsw) * 8;
      f16x8 a0[4], bfr[4];
#pragma unroll
      for (int j = 0; j < 4; ++j)
        bfr[j] = *(const f16x8*)(Bs + (wn + j * 16 + mfrag) * 64 + c0);
#pragma unroll
      for (int i = 0; i < 4; ++i)
        a0[i] = *(const f16x8*)(Ash + (wm + i * 16 + mfrag) * 64 + c0);
#pragma unroll
      for (int i = 0; i < 4; ++i)
#pragma unroll
        for (int j = 0; j < 4; ++j)
          acc[i][j] = __builtin_amdgcn_mfma_f32_16x16x32_f16(a0[i], bfr[j], acc[i][j], 0, 0, 0);
#pragma unroll
      for (int i = 0; i < 4; ++i)
        a0[i] = *(const f16x8*)(Asl + (wm + i * 16 + mfrag) * 64 + c0);
#pragma unroll
      for (int i = 0; i < 4; ++i)
#pragma unroll
        for (int j = 0; j < 4; ++j)
          acc[i][j] = __builtin_amdgcn_mfma_f32_16x16x32_f16(a0[i], bfr[j], acc[i][j], 0, 0, 0);
    }
    __syncthreads();
  }
  float* Cc = C + (size_t)kc * chunkStride;
#pragma unroll
  for (int i = 0; i < 4; ++i)
#pragma unroll
    for (int j = 0; j < 4; ++j)
#pragma unroll
      for (int rr = 0; rr < 4; ++rr) {
        int row = m0 + wm + i * 16 + quad * 4 + rr;
        int col = n0 + wn + j * 16 + mfrag;
        Cc[(size_t)row * ldc + col] = acc[i][j][rr];
      }
}

extern "C" void kernel_launch(void* const* d_in, const int* in_sizes, int n_in,
                              void* d_out, int out_size, void* d_ws, size_t ws_size,
                              hipStream_t stream) {
  const float* x  = (const float*)d_in[0];
  const float* Wk = (const float*)d_in[1];
  const float* Wq = (const float*)d_in[2];
  const float* W2 = (const float*)d_in[3];

  char* ws = (char*)d_ws;
  const size_t MB = 1024 * 1024;
  // persistent region [0, 75 MB)
  u16*   QKf  = (u16*)  (ws + 0);            //  2 MB  [4096,256] f16 (q | k)
  u16*   Wf   = (u16*)  (ws + 2 * MB);       //  1 MB  [256,2048] (Wq ; Wk) f16
  u16*   xT   = (u16*)  (ws + 3 * MB);       // 16 MB  [2048,4096] f16
  u16*   W2f  = (u16*)  (ws + 19 * MB);      //  8 MB  [2048,2048] f16
  u16*   outb = (u16*)  (ws + 27 * MB);      // 16 MB  [4096,2048] f16
  u16*   attn = (u16*)  (ws + 43 * MB);      // 32 MB  [4096,4096] f16
  // reusable region A [75, 139 MB) — lifetimes strictly sequential:
  u16*   xh   = (u16*)  (ws + 75 * MB);      // 16 MB  (dead after qk gemm)
  u16*   xl   = (u16*)  (ws + 91 * MB);      // 16 MB  (dead after qk gemm)
  float* QKp  = (float*)(ws + 107 * MB);     // 32 MB  8 x [4096,256] partials
  float* S    = (float*)(ws + 75 * MB);      // 64 MB  scores (after xh/xl/QKp dead)
  u16*   Ph   = (u16*)  (ws + 75 * MB);      // 32 MB  2 x [4096,2048] f16 partials (after S dead)

  const int QKN4 = NCTX * 256 / 4;
  const size_t CS = (size_t)NCTX * DMODEL;   // partial chunk stride (elements)

  // fused prep: x f16-split + f16 transpose + W/W2 casts
  prep_all<<<6656, 256, 0, stream>>>(x, Wq, Wk, W2, xh, xl, Wf, W2f, xT);

  // q,k = (xh+xl) @ [Wq;Wk]^T  (f16x2 2-pass), split-K KC=256 -> 512 blocks
  gemm_f16x2_p<<<dim3(NCTX / 128, 2, 8), 256, 0, stream>>>(
      xh, xl, Wf, QKp, DMODEL, DMODEL, 256, DMODEL, 256, (size_t)NCTX * 256);
  reduce8_f16<<<(QKN4 + 255) / 256, 256, 0, stream>>>(QKp, QKf, QKN4);

  // scores = q @ k^T, single-pass f16, lower-triangular tiles, direct fp32 store
  gemm_f16_p<<<dim3(NCTX / 128, NCTX / 128, 1), 256, 0, stream>>>(
      QKf, QKf + DHEAD, S, 256, 256, NCTX, DHEAD, DHEAD, 0, 0, 1);
  softmax_rows<<<NCTX, 256, 0, stream>>>(S, attn);

  // out = attn @ x (causal): z=2, KC=2048; rows<2048 stored final-direct to outb,
  // rows>=2048 as f16 partials -> reduce_c2
  gemm_f16_h<<<dim3(NCTX / 128, DMODEL / 128, 2), 256, 0, stream>>>(
      attn, xT, Ph, outb, NCTX, NCTX, DMODEL, NCTX, 2048, CS, 1);
  reduce_c2<<<2048, 256, 0, stream>>>(Ph, outb, CS);

  // final = out @ W2^T: z=1, K=2048 unsplit, direct fp32 store to d_out
  gemm_f16_p<<<dim3(NCTX / 128, DMODEL / 128, 1), 256, 0, stream>>>(
      outb, W2f, (float*)d_out, DMODEL, DMODEL, DMODEL, DMODEL, DMODEL, 0, 0, 0);
}

// Round 4
// 238.568 us; speedup vs baseline: 1.1377x; 1.0765x over previous
//
#include <hip/hip_runtime.h>

#define NCTX 4096
#define DMODEL 2048
#define DHEAD 128

typedef _Float16 f16;
typedef f16 f16x8 __attribute__((ext_vector_type(8)));
typedef float f32x4 __attribute__((ext_vector_type(4)));
typedef unsigned short u16;
typedef u16 u16x8 __attribute__((ext_vector_type(8)));

__device__ __forceinline__ u16 f2h(float f) {
  union { f16 h; u16 u; } v; v.h = (f16)f; return v.u;
}
__device__ __forceinline__ float h2f(u16 u) {
  union { u16 u; f16 h; } v; v.u = u; return (float)v.h;
}

__device__ __forceinline__ void gl_lds16(const void* g, void* l) {
  __builtin_amdgcn_global_load_lds((const __attribute__((address_space(1))) void*)g,
                                   (__attribute__((address_space(3))) void*)l, 16, 0, 0);
}

// fp32 -> (hi, lo) f16 split: hi+lo represents x to ~2^-22
__device__ __forceinline__ void splitH4(float4 v, ushort4& h, ushort4& l) {
  h.x = f2h(v.x); l.x = f2h(v.x - h2f(h.x));
  h.y = f2h(v.y); l.y = f2h(v.y - h2f(h.y));
  h.z = f2h(v.z); l.z = f2h(v.z - h2f(h.z));
  h.w = f2h(v.w); l.w = f2h(v.w - h2f(h.w));
}

// ------------- fused prep: x f16-split + f16-transpose | W casts | W2 cast ----------
__global__ __launch_bounds__(256) void prep_all(const float* __restrict__ x,
                                                const float* __restrict__ Wq,
                                                const float* __restrict__ Wk,
                                                const float* __restrict__ W2,
                                                u16* __restrict__ xh, u16* __restrict__ xl,
                                                u16* __restrict__ Wf, u16* __restrict__ W2f,
                                                u16* __restrict__ XT) {
  __shared__ float tile[64][65];
  int b = blockIdx.x;
  int t = threadIdx.x;
  if (b < 2048) {
    int mb = (b >> 5) * 64, db = (b & 31) * 64;
    int tx = t & 15, ty = t >> 4;
#pragma unroll
    for (int rr = 0; rr < 4; ++rr) {
      int row = rr * 16 + ty;
      float4 v = *(const float4*)(x + (size_t)(mb + row) * DMODEL + db + tx * 4);
      ushort4 h, l; splitH4(v, h, l);
      size_t gi = ((size_t)(mb + row) * DMODEL + db) / 4 + tx;
      ((ushort4*)xh)[gi] = h; ((ushort4*)xl)[gi] = l;
      tile[row][tx * 4 + 0] = v.x; tile[row][tx * 4 + 1] = v.y;
      tile[row][tx * 4 + 2] = v.z; tile[row][tx * 4 + 3] = v.w;
    }
    __syncthreads();
#pragma unroll
    for (int rr = 0; rr < 4; ++rr) {
      int r = (t >> 4) * 4 + rr;
      int c0 = (t & 15) * 4;
      ushort4 o;
      o.x = f2h(tile[c0 + 0][r]); o.y = f2h(tile[c0 + 1][r]);
      o.z = f2h(tile[c0 + 2][r]); o.w = f2h(tile[c0 + 3][r]);
      *(ushort4*)(XT + (size_t)(db + r) * NCTX + mb + c0) = o;
    }
  } else if (b < 2560) {               // cast Wq | Wk (single f16)
    int wk = (b >= 2304);
    int i = (b - (wk ? 2304 : 2048)) * 256 + t;
    const float* W = wk ? Wk : Wq;
    size_t off = wk ? ((size_t)DHEAD * DMODEL / 4) : 0;
    float4 v = ((const float4*)W)[i];
    ushort4 o;
    o.x = f2h(v.x); o.y = f2h(v.y); o.z = f2h(v.z); o.w = f2h(v.w);
    ((ushort4*)Wf)[off + i] = o;
  } else {                             // cast W2
    int i = (b - 2560) * 256 + t;
    float4 v = ((const float4*)W2)[i];
    ushort4 o;
    o.x = f2h(v.x); o.y = f2h(v.y); o.z = f2h(v.z); o.w = f2h(v.w);
    ((ushort4*)W2f)[i] = o;
  }
}

// ---------------- 8-way split-K reduce (fp32 in) -> f16 ----------------
__global__ __launch_bounds__(256) void reduce8_f16(const float* __restrict__ P,
                                                   u16* __restrict__ out, int n4) {
  int i = blockIdx.x * 256 + threadIdx.x;
  if (i >= n4) return;
  float4 s = ((const float4*)P)[i];
#pragma unroll
  for (int z = 1; z < 8; ++z) {
    float4 v = ((const float4*)P)[(size_t)z * n4 + i];
    s.x += v.x; s.y += v.y; s.z += v.z; s.w += v.w;
  }
  ushort4 o;
  o.x = f2h(s.x); o.y = f2h(s.y); o.z = f2h(s.z); o.w = f2h(s.w);
  ((ushort4*)out)[i] = o;
}

// ---------------- causal 2-chunk f16 split-K reduce (rows >= 2048 only) ----------
__global__ __launch_bounds__(256) void reduce_c2(const u16* __restrict__ P,
                                                 u16* __restrict__ out, size_t cs) {
  int row = 2048 + blockIdx.x;
  int t = threadIdx.x;
  size_t base = (size_t)row * DMODEL + t * 8;
  u16x8 a = *(const u16x8*)(P + base);
  u16x8 b = *(const u16x8*)(P + cs + base);
  u16x8 o;
#pragma unroll
  for (int k = 0; k < 8; ++k) o[k] = f2h(h2f(a[k]) + h2f(b[k]));
  *(u16x8*)(out + base) = o;
}

// ---------------- row softmax (fp32) -> f16 attn ----------------
__global__ __launch_bounds__(256) void softmax_rows(const float* __restrict__ S,
                                                    u16* __restrict__ P) {
  int i = blockIdx.x;
  int t = threadIdx.x;
  __shared__ float rowbuf[NCTX];
  __shared__ float red[4];
  __shared__ float red2[4];
  const float* srow = S + (size_t)i * NCTX;
  int len = i + 1;
  int jmax = ((i >> 7) + 1) << 7;  // causal gemm reads j < 128*(bm+1)
  float mx = -3.0e38f;
  for (int j = t * 4; j < len; j += 1024) {
    if (j + 4 <= len) {
      float4 v = *(const float4*)(srow + j);
      *(float4*)(rowbuf + j) = v;
      mx = fmaxf(mx, fmaxf(fmaxf(v.x, v.y), fmaxf(v.z, v.w)));
    } else {
      for (int k = j; k < len; ++k) {
        float v = srow[k];
        rowbuf[k] = v;
        mx = fmaxf(mx, v);
      }
    }
  }
#pragma unroll
  for (int o = 32; o > 0; o >>= 1) mx = fmaxf(mx, __shfl_xor(mx, o, 64));
  if ((t & 63) == 0) red[t >> 6] = mx;
  __syncthreads();
  mx = fmaxf(fmaxf(red[0], red[1]), fmaxf(red[2], red[3]));
  float sum = 0.f;
  for (int j = t; j < len; j += 256) {
    float e = __expf(rowbuf[j] - mx);
    rowbuf[j] = e;
    sum += e;
  }
#pragma unroll
  for (int o = 32; o > 0; o >>= 1) sum += __shfl_xor(sum, o, 64);
  if ((t & 63) == 0) red2[t >> 6] = sum;
  __syncthreads();
  float inv = 1.0f / (red2[0] + red2[1] + red2[2] + red2[3]);
  u16* prow = P + (size_t)i * NCTX;
  for (int j = t * 4; j < jmax; j += 1024) {
    ushort4 o;
    o.x = (j + 0 < len) ? f2h(rowbuf[j + 0] * inv) : (u16)0;
    o.y = (j + 1 < len) ? f2h(rowbuf[j + 1] * inv) : (u16)0;
    o.z = (j + 2 < len) ? f2h(rowbuf[j + 2] * inv) : (u16)0;
    o.w = (j + 3 < len) ? f2h(rowbuf[j + 3] * inv) : (u16)0;
    *(ushort4*)(prow + j) = o;
  }
}

// ---------------- f16 MFMA GEMM, B^T, 128x128, BK=64, XOR swizzle, fp32 out -------
// scores (tri=1, skip bn>bm tiles) and out@W2 (z=1 direct fp32 store to d_out).
__global__ __launch_bounds__(256, 4) void gemm_f16_p(const u16* __restrict__ A,
                                                     const u16* __restrict__ B,
                                                     float* __restrict__ C,
                                                     int lda, int ldb, int ldc,
                                                     int K, int KC, size_t chunkStride,
                                                     int causal, int tri) {
  int bm = gridDim.x - 1 - blockIdx.x, bn = blockIdx.y, kc = blockIdx.z;
  if (tri && bn > bm) return;
  int kEnd = K;
  if (causal) { int ke = (bm + 1) * 128; if (ke < kEnd) kEnd = ke; }
  int kStart = kc * KC;
  if (kStart >= kEnd) return;
  int kStop = kStart + KC < kEnd ? kStart + KC : kEnd;
  __shared__ __align__(16) u16 As[128 * 64];
  __shared__ __align__(16) u16 Bs[128 * 64];
  int t = threadIdx.x;
  int lane = t & 63, w = t >> 6;
  int m0 = bm * 128, n0 = bn * 128;
  int wm = (w >> 1) * 64, wn = (w & 1) * 64;
  int mfrag = lane & 15, quad = lane >> 4;
  int srow = t >> 3, schunk = t & 7;
  int rsw = mfrag & 7;
  f32x4 acc[4][4] = {};
  for (int kt = kStart; kt < kStop; kt += 64) {
#pragma unroll
    for (int p = 0; p < 4; ++p) {
      int row = p * 32 + srow;
      int gsc = schunk ^ (row & 7);
      gl_lds16(A + (size_t)(m0 + row) * lda + kt + gsc * 8, As + (size_t)(p * 256 + t) * 8);
      gl_lds16(B + (size_t)(n0 + row) * ldb + kt + gsc * 8, Bs + (size_t)(p * 256 + t) * 8);
    }
    __syncthreads();
#pragma unroll
    for (int ks = 0; ks < 2; ++ks) {
      int c0 = ((ks * 4 + quad) ^ rsw) * 8;
      f16x8 af[4], bfr[4];
#pragma unroll
      for (int i = 0; i < 4; ++i)
        af[i] = *(const f16x8*)(As + (wm + i * 16 + mfrag) * 64 + c0);
#pragma unroll
      for (int j = 0; j < 4; ++j)
        bfr[j] = *(const f16x8*)(Bs + (wn + j * 16 + mfrag) * 64 + c0);
#pragma unroll
      for (int i = 0; i < 4; ++i)
#pragma unroll
        for (int j = 0; j < 4; ++j)
          acc[i][j] = __builtin_amdgcn_mfma_f32_16x16x32_f16(af[i], bfr[j], acc[i][j], 0, 0, 0);
    }
    __syncthreads();
  }
  float* Cc = C + (size_t)kc * chunkStride;
#pragma unroll
  for (int i = 0; i < 4; ++i)
#pragma unroll
    for (int j = 0; j < 4; ++j)
#pragma unroll
      for (int rr = 0; rr < 4; ++rr) {
        int row = m0 + wm + i * 16 + quad * 4 + rr;
        int col = n0 + wn + j * 16 + mfrag;
        Cc[(size_t)row * ldc + col] = acc[i][j][rr];
      }
}

// ---------------- attn@x causal GEMM: packed, size-balanced 1D grid --------------
// 768 real (bm,bn,kc) work items, sorted by descending K-work and snake-striped
// so each CU's ~3 blocks sum to ~66 BK-units regardless of assignment order.
// rank layout (desc by size s=2k units):
//   r in [0,272): bm=15+r/16, bn=r%16, kc=0            (32 units)
//   r in [272,288): bm=31, bn=r-272, kc=1              (32 units)
//   r >= 288: g=(r-288)/32, k=15-g, j=(r-288)%32:
//     j<16 -> (bm=k-1, bn=j, kc=0); else (bm=15+k, bn=j-16, kc=1)   (2k units)
// snake stripes: bid b: s=b/256, c=b%256; rank = s==0 ? c : s==1 ? 511-c : 512+c
__global__ __launch_bounds__(256, 4) void gemm_attnx(const u16* __restrict__ A,
                                                     const u16* __restrict__ B,
                                                     u16* __restrict__ C,
                                                     u16* __restrict__ Cf,
                                                     size_t chunkStride) {
  int b = blockIdx.x;
  int s = b >> 8, c = b & 255;
  int r = (s == 0) ? c : (s == 1) ? (511 - c) : (512 + c);
  int bm, bn, kc;
  if (r < 272) {
    bm = 15 + (r >> 4); bn = r & 15; kc = 0;
  } else if (r < 288) {
    bm = 31; bn = r - 272; kc = 1;
  } else {
    int g = (r - 288) >> 5, j = (r - 288) & 31;
    int k = 15 - g;
    if (j < 16) { bm = k - 1; bn = j; kc = 0; }
    else        { bm = 15 + k; bn = j - 16; kc = 1; }
  }
  int kEnd = (bm + 1) * 128;
  if (kEnd > NCTX) kEnd = NCTX;
  int kStart = kc * 2048;
  int kStop = kStart + 2048 < kEnd ? kStart + 2048 : kEnd;
  __shared__ __align__(16) u16 As[128 * 64];
  __shared__ __align__(16) u16 Bs[128 * 64];
  int t = threadIdx.x;
  int lane = t & 63, w = t >> 6;
  int m0 = bm * 128, n0 = bn * 128;
  int wm = (w >> 1) * 64, wn = (w & 1) * 64;
  int mfrag = lane & 15, quad = lane >> 4;
  int srow = t >> 3, schunk = t & 7;
  int rsw = mfrag & 7;
  f32x4 acc[4][4] = {};
  for (int kt = kStart; kt < kStop; kt += 64) {
#pragma unroll
    for (int p = 0; p < 4; ++p) {
      int row = p * 32 + srow;
      int gsc = schunk ^ (row & 7);
      gl_lds16(A + (size_t)(m0 + row) * NCTX + kt + gsc * 8, As + (size_t)(p * 256 + t) * 8);
      gl_lds16(B + (size_t)(n0 + row) * NCTX + kt + gsc * 8, Bs + (size_t)(p * 256 + t) * 8);
    }
    __syncthreads();
#pragma unroll
    for (int ks = 0; ks < 2; ++ks) {
      int c0 = ((ks * 4 + quad) ^ rsw) * 8;
      f16x8 af[4], bfr[4];
#pragma unroll
      for (int i = 0; i < 4; ++i)
        af[i] = *(const f16x8*)(As + (wm + i * 16 + mfrag) * 64 + c0);
#pragma unroll
      for (int j = 0; j < 4; ++j)
        bfr[j] = *(const f16x8*)(Bs + (wn + j * 16 + mfrag) * 64 + c0);
#pragma unroll
      for (int i = 0; i < 4; ++i)
#pragma unroll
        for (int j = 0; j < 4; ++j)
          acc[i][j] = __builtin_amdgcn_mfma_f32_16x16x32_f16(af[i], bfr[j], acc[i][j], 0, 0, 0);
    }
    __syncthreads();
  }
  // bm<16: chunk covers whole causal K -> final-direct to Cf; else f16 partial.
  u16* Cc = (kc == 0 && kEnd <= 2048) ? Cf : (C + (size_t)kc * chunkStride);
#pragma unroll
  for (int i = 0; i < 4; ++i)
#pragma unroll
    for (int j = 0; j < 4; ++j)
#pragma unroll
      for (int rr = 0; rr < 4; ++rr) {
        int row = m0 + wm + i * 16 + quad * 4 + rr;
        int col = n0 + wn + j * 16 + mfrag;
        Cc[(size_t)row * DMODEL + col] = f2h(acc[i][j][rr]);
      }
}

// ---------------- f16x2 split-A MFMA GEMM (qk projection) -------------------------
__global__ __launch_bounds__(256, 3) void gemm_f16x2_p(const u16* __restrict__ Ah,
                                                       const u16* __restrict__ Al,
                                                       const u16* __restrict__ B,
                                                       float* __restrict__ C,
                                                       int lda, int ldb, int ldc,
                                                       int K, int KC, size_t chunkStride) {
  int bm = blockIdx.x, bn = blockIdx.y, kc = blockIdx.z;
  int kStart = kc * KC;
  int kStop = kStart + KC < K ? kStart + KC : K;
  __shared__ __align__(16) u16 Ash[128 * 64];
  __shared__ __align__(16) u16 Asl[128 * 64];
  __shared__ __align__(16) u16 Bs[128 * 64];
  int t = threadIdx.x;
  int lane = t & 63, w = t >> 6;
  int m0 = bm * 128, n0 = bn * 128;
  int wm = (w >> 1) * 64, wn = (w & 1) * 64;
  int mfrag = lane & 15, quad = lane >> 4;
  int srow = t >> 3, schunk = t & 7;
  int rsw = mfrag & 7;
  f32x4 acc[4][4] = {};
  for (int kt = kStart; kt < kStop; kt += 64) {
#pragma unroll
    for (int p = 0; p < 4; ++p) {
      int row = p * 32 + srow;
      int gsc = schunk ^ (row & 7);
      size_t aoff = (size_t)(m0 + row) * lda + kt + gsc * 8;
      size_t loff = (size_t)(p * 256 + t) * 8;
      gl_lds16(Ah + aoff, Ash + loff);
      gl_lds16(Al + aoff, Asl + loff);
      gl_lds16(B + (size_t)(n0 + row) * ldb + kt + gsc * 8, Bs + loff);
    }
    __syncthreads();
#pragma unroll
    for (int ks = 0; ks < 2; ++ks) {
      int c0 = ((ks * 4 + quad) ^ rsw) * 8;
      f16x8 a0[4], bfr[4];
#pragma unroll
      for (int j = 0; j < 4; ++j)
        bfr[j] = *(const f16x8*)(Bs + (wn + j * 16 + mfrag) * 64 + c0);
#pragma unroll
      for (int i = 0; i < 4; ++i)
        a0[i] = *(const f16x8*)(Ash + (wm + i * 16 + mfrag) * 64 + c0);
#pragma unroll
      for (int i = 0; i < 4; ++i)
#pragma unroll
        for (int j = 0; j < 4; ++j)
          acc[i][j] = __builtin_amdgcn_mfma_f32_16x16x32_f16(a0[i], bfr[j], acc[i][j], 0, 0, 0);
#pragma unroll
      for (int i = 0; i < 4; ++i)
        a0[i] = *(const f16x8*)(Asl + (wm + i * 16 + mfrag) * 64 + c0);
#pragma unroll
      for (int i = 0; i < 4; ++i)
#pragma unroll
        for (int j = 0; j < 4; ++j)
          acc[i][j] = __builtin_amdgcn_mfma_f32_16x16x32_f16(a0[i], bfr[j], acc[i][j], 0, 0, 0);
    }
    __syncthreads();
  }
  float* Cc = C + (size_t)kc * chunkStride;
#pragma unroll
  for (int i = 0; i < 4; ++i)
#pragma unroll
    for (int j = 0; j < 4; ++j)
#pragma unroll
      for (int rr = 0; rr < 4; ++rr) {
        int row = m0 + wm + i * 16 + quad * 4 + rr;
        int col = n0 + wn + j * 16 + mfrag;
        Cc[(size_t)row * ldc + col] = acc[i][j][rr];
      }
}

extern "C" void kernel_launch(void* const* d_in, const int* in_sizes, int n_in,
                              void* d_out, int out_size, void* d_ws, size_t ws_size,
                              hipStream_t stream) {
  const float* x  = (const float*)d_in[0];
  const float* Wk = (const float*)d_in[1];
  const float* Wq = (const float*)d_in[2];
  const float* W2 = (const float*)d_in[3];

  char* ws = (char*)d_ws;
  const size_t MB = 1024 * 1024;
  // persistent region [0, 75 MB)
  u16*   QKf  = (u16*)  (ws + 0);            //  2 MB  [4096,256] f16 (q | k)
  u16*   Wf   = (u16*)  (ws + 2 * MB);       //  1 MB  [256,2048] (Wq ; Wk) f16
  u16*   xT   = (u16*)  (ws + 3 * MB);       // 16 MB  [2048,4096] f16
  u16*   W2f  = (u16*)  (ws + 19 * MB);      //  8 MB  [2048,2048] f16
  u16*   outb = (u16*)  (ws + 27 * MB);      // 16 MB  [4096,2048] f16
  u16*   attn = (u16*)  (ws + 43 * MB);      // 32 MB  [4096,4096] f16
  // reusable region A [75, 139 MB) — lifetimes strictly sequential:
  u16*   xh   = (u16*)  (ws + 75 * MB);      // 16 MB  (dead after qk gemm)
  u16*   xl   = (u16*)  (ws + 91 * MB);      // 16 MB  (dead after qk gemm)
  float* QKp  = (float*)(ws + 107 * MB);     // 32 MB  8 x [4096,256] partials
  float* S    = (float*)(ws + 75 * MB);      // 64 MB  scores (after xh/xl/QKp dead)
  u16*   Ph   = (u16*)  (ws + 75 * MB);      // 32 MB  2 x [4096,2048] f16 partials (after S dead)

  const int QKN4 = NCTX * 256 / 4;
  const size_t CS = (size_t)NCTX * DMODEL;   // partial chunk stride (elements)

  // fused prep: x f16-split + f16 transpose + W/W2 casts
  prep_all<<<6656, 256, 0, stream>>>(x, Wq, Wk, W2, xh, xl, Wf, W2f, xT);

  // q,k = (xh+xl) @ [Wq;Wk]^T  (f16x2 2-pass), split-K KC=256 -> 512 blocks
  gemm_f16x2_p<<<dim3(NCTX / 128, 2, 8), 256, 0, stream>>>(
      xh, xl, Wf, QKp, DMODEL, DMODEL, 256, DMODEL, 256, (size_t)NCTX * 256);
  reduce8_f16<<<(QKN4 + 255) / 256, 256, 0, stream>>>(QKp, QKf, QKN4);

  // scores = q @ k^T, single-pass f16, lower-triangular tiles, direct fp32 store
  gemm_f16_p<<<dim3(NCTX / 128, NCTX / 128, 1), 256, 0, stream>>>(
      QKf, QKf + DHEAD, S, 256, 256, NCTX, DHEAD, DHEAD, 0, 0, 1);
  softmax_rows<<<NCTX, 256, 0, stream>>>(S, attn);

  // out = attn @ x (causal): packed 768-block balanced grid; rows<2048
  // final-direct to outb, rows>=2048 f16 partials -> reduce_c2
  gemm_attnx<<<768, 256, 0, stream>>>(attn, xT, Ph, outb, CS);
  reduce_c2<<<2048, 256, 0, stream>>>(Ph, outb, CS);

  // final = out @ W2^T: z=1, K=2048 unsplit, direct fp32 store to d_out
  gemm_f16_p<<<dim3(NCTX / 128, DMODEL / 128, 1), 256, 0, stream>>>(
      outb, W2f, (float*)d_out, DMODEL, DMODEL, DMODEL, DMODEL, DMODEL, 0, 0, 0);
}

// Round 5
// 225.923 us; speedup vs baseline: 1.2013x; 1.0560x over previous
//
#include <hip/hip_runtime.h>

#define NCTX 4096
#define DMODEL 2048
#define DHEAD 128

typedef _Float16 f16;
typedef f16 f16x8 __attribute__((ext_vector_type(8)));
typedef float f32x4 __attribute__((ext_vector_type(4)));
typedef unsigned short u16;
typedef u16 u16x8 __attribute__((ext_vector_type(8)));

__device__ __forceinline__ u16 f2h(float f) {
  union { f16 h; u16 u; } v; v.h = (f16)f; return v.u;
}
__device__ __forceinline__ float h2f(u16 u) {
  union { u16 u; f16 h; } v; v.u = u; return (float)v.h;
}

__device__ __forceinline__ void gl_lds16(const void* g, void* l) {
  __builtin_amdgcn_global_load_lds((const __attribute__((address_space(1))) void*)g,
                                   (__attribute__((address_space(3))) void*)l, 16, 0, 0);
}

// fp32 -> (hi, lo) f16 split: hi+lo represents x to ~2^-22
__device__ __forceinline__ void splitH4(float4 v, ushort4& h, ushort4& l) {
  h.x = f2h(v.x); l.x = f2h(v.x - h2f(h.x));
  h.y = f2h(v.y); l.y = f2h(v.y - h2f(h.y));
  h.z = f2h(v.z); l.z = f2h(v.z - h2f(h.z));
  h.w = f2h(v.w); l.w = f2h(v.w - h2f(h.w));
}

// ------------- fused prep: x f16-split + f16-transpose | W casts | W2 cast ----------
__global__ __launch_bounds__(256) void prep_all(const float* __restrict__ x,
                                                const float* __restrict__ Wq,
                                                const float* __restrict__ Wk,
                                                const float* __restrict__ W2,
                                                u16* __restrict__ xh, u16* __restrict__ xl,
                                                u16* __restrict__ Wf, u16* __restrict__ W2f,
                                                u16* __restrict__ XT) {
  __shared__ float tile[64][65];
  int b = blockIdx.x;
  int t = threadIdx.x;
  if (b < 2048) {
    int mb = (b >> 5) * 64, db = (b & 31) * 64;
    int tx = t & 15, ty = t >> 4;
#pragma unroll
    for (int rr = 0; rr < 4; ++rr) {
      int row = rr * 16 + ty;
      float4 v = *(const float4*)(x + (size_t)(mb + row) * DMODEL + db + tx * 4);
      ushort4 h, l; splitH4(v, h, l);
      size_t gi = ((size_t)(mb + row) * DMODEL + db) / 4 + tx;
      ((ushort4*)xh)[gi] = h; ((ushort4*)xl)[gi] = l;
      tile[row][tx * 4 + 0] = v.x; tile[row][tx * 4 + 1] = v.y;
      tile[row][tx * 4 + 2] = v.z; tile[row][tx * 4 + 3] = v.w;
    }
    __syncthreads();
#pragma unroll
    for (int rr = 0; rr < 4; ++rr) {
      int r = (t >> 4) * 4 + rr;
      int c0 = (t & 15) * 4;
      ushort4 o;
      o.x = f2h(tile[c0 + 0][r]); o.y = f2h(tile[c0 + 1][r]);
      o.z = f2h(tile[c0 + 2][r]); o.w = f2h(tile[c0 + 3][r]);
      *(ushort4*)(XT + (size_t)(db + r) * NCTX + mb + c0) = o;
    }
  } else if (b < 2560) {               // cast Wq | Wk (single f16)
    int wk = (b >= 2304);
    int i = (b - (wk ? 2304 : 2048)) * 256 + t;
    const float* W = wk ? Wk : Wq;
    size_t off = wk ? ((size_t)DHEAD * DMODEL / 4) : 0;
    float4 v = ((const float4*)W)[i];
    ushort4 o;
    o.x = f2h(v.x); o.y = f2h(v.y); o.z = f2h(v.z); o.w = f2h(v.w);
    ((ushort4*)Wf)[off + i] = o;
  } else {                             // cast W2
    int i = (b - 2560) * 256 + t;
    float4 v = ((const float4*)W2)[i];
    ushort4 o;
    o.x = f2h(v.x); o.y = f2h(v.y); o.z = f2h(v.z); o.w = f2h(v.w);
    ((ushort4*)W2f)[i] = o;
  }
}

// ---------------- 8-way split-K reduce (f16 partials in) -> f16 ----------------
__global__ __launch_bounds__(256) void reduce8h(const u16* __restrict__ P,
                                                u16* __restrict__ out, int n8) {
  int i = blockIdx.x * 256 + threadIdx.x;
  if (i >= n8) return;
  float s[8] = {};
#pragma unroll
  for (int z = 0; z < 8; ++z) {
    u16x8 v = ((const u16x8*)P)[(size_t)z * n8 + i];
#pragma unroll
    for (int k = 0; k < 8; ++k) s[k] += h2f(v[k]);
  }
  u16x8 o;
#pragma unroll
  for (int k = 0; k < 8; ++k) o[k] = f2h(s[k]);
  ((u16x8*)out)[i] = o;
}

// ---------------- causal 2-chunk f16 split-K reduce (rows >= 2048 only) ----------
__global__ __launch_bounds__(256) void reduce_c2(const u16* __restrict__ P,
                                                 u16* __restrict__ out, size_t cs) {
  int row = 2048 + blockIdx.x;
  int t = threadIdx.x;
  size_t base = (size_t)row * DMODEL + t * 8;
  u16x8 a = *(const u16x8*)(P + base);
  u16x8 b = *(const u16x8*)(P + cs + base);
  u16x8 o;
#pragma unroll
  for (int k = 0; k < 8; ++k) o[k] = f2h(h2f(a[k]) + h2f(b[k]));
  *(u16x8*)(out + base) = o;
}

// ---------------- row softmax, one wave per row, row held in registers ----------
// grid 1024 x 256: wave w of block b handles row b*4+w. No LDS, no syncthreads.
__global__ __launch_bounds__(256) void softmax_wave(const float* __restrict__ S,
                                                    u16* __restrict__ P) {
  int t = threadIdx.x;
  int lane = t & 63, w = t >> 6;
  int row = blockIdx.x * 4 + w;
  const float* srow = S + (size_t)row * NCTX;
  int len = row + 1;
  int jmax = ((row >> 7) + 1) << 7;  // causal gemm reads j < 128*(bm+1)
  float4 v[16];
  float mx = -3.0e38f;
#pragma unroll
  for (int k = 0; k < 16; ++k) {
    int j = k * 256 + lane * 4;
    if (j < jmax) {
      float4 x = *(const float4*)(srow + j);
      x.x = (j + 0 < len) ? x.x : -3.0e38f;
      x.y = (j + 1 < len) ? x.y : -3.0e38f;
      x.z = (j + 2 < len) ? x.z : -3.0e38f;
      x.w = (j + 3 < len) ? x.w : -3.0e38f;
      v[k] = x;
      mx = fmaxf(mx, fmaxf(fmaxf(x.x, x.y), fmaxf(x.z, x.w)));
    }
  }
#pragma unroll
  for (int o = 32; o > 0; o >>= 1) mx = fmaxf(mx, __shfl_xor(mx, o, 64));
  float sum = 0.f;
#pragma unroll
  for (int k = 0; k < 16; ++k) {
    int j = k * 256 + lane * 4;
    if (j < jmax) {
      float4 x = v[k];
      x.x = (j + 0 < len) ? __expf(x.x - mx) : 0.f;
      x.y = (j + 1 < len) ? __expf(x.y - mx) : 0.f;
      x.z = (j + 2 < len) ? __expf(x.z - mx) : 0.f;
      x.w = (j + 3 < len) ? __expf(x.w - mx) : 0.f;
      v[k] = x;
      sum += x.x + x.y + x.z + x.w;
    }
  }
#pragma unroll
  for (int o = 32; o > 0; o >>= 1) sum += __shfl_xor(sum, o, 64);
  float inv = 1.0f / sum;
  u16* prow = P + (size_t)row * NCTX;
#pragma unroll
  for (int k = 0; k < 16; ++k) {
    int j = k * 256 + lane * 4;
    if (j < jmax) {
      float4 x = v[k];
      ushort4 o4;
      o4.x = f2h(x.x * inv); o4.y = f2h(x.y * inv);
      o4.z = f2h(x.z * inv); o4.w = f2h(x.w * inv);
      *(ushort4*)(prow + j) = o4;
    }
  }
}

// ---------------- f16 MFMA GEMM, B^T, 128x128, BK=64, XOR swizzle, fp32 out -------
// scores (tri=1, skip bn>bm tiles) and out@W2 (z=1 direct fp32 store to d_out).
__global__ __launch_bounds__(256, 4) void gemm_f16_p(const u16* __restrict__ A,
                                                     const u16* __restrict__ B,
                                                     float* __restrict__ C,
                                                     int lda, int ldb, int ldc,
                                                     int K, int KC, size_t chunkStride,
                                                     int causal, int tri) {
  int bm = gridDim.x - 1 - blockIdx.x, bn = blockIdx.y, kc = blockIdx.z;
  if (tri && bn > bm) return;
  int kEnd = K;
  if (causal) { int ke = (bm + 1) * 128; if (ke < kEnd) kEnd = ke; }
  int kStart = kc * KC;
  if (kStart >= kEnd) return;
  int kStop = kStart + KC < kEnd ? kStart + KC : kEnd;
  __shared__ __align__(16) u16 As[128 * 64];
  __shared__ __align__(16) u16 Bs[128 * 64];
  int t = threadIdx.x;
  int lane = t & 63, w = t >> 6;
  int m0 = bm * 128, n0 = bn * 128;
  int wm = (w >> 1) * 64, wn = (w & 1) * 64;
  int mfrag = lane & 15, quad = lane >> 4;
  int srow = t >> 3, schunk = t & 7;
  int rsw = mfrag & 7;
  f32x4 acc[4][4] = {};
  for (int kt = kStart; kt < kStop; kt += 64) {
#pragma unroll
    for (int p = 0; p < 4; ++p) {
      int row = p * 32 + srow;
      int gsc = schunk ^ (row & 7);
      gl_lds16(A + (size_t)(m0 + row) * lda + kt + gsc * 8, As + (size_t)(p * 256 + t) * 8);
      gl_lds16(B + (size_t)(n0 + row) * ldb + kt + gsc * 8, Bs + (size_t)(p * 256 + t) * 8);
    }
    __syncthreads();
#pragma unroll
    for (int ks = 0; ks < 2; ++ks) {
      int c0 = ((ks * 4 + quad) ^ rsw) * 8;
      f16x8 af[4], bfr[4];
#pragma unroll
      for (int i = 0; i < 4; ++i)
        af[i] = *(const f16x8*)(As + (wm + i * 16 + mfrag) * 64 + c0);
#pragma unroll
      for (int j = 0; j < 4; ++j)
        bfr[j] = *(const f16x8*)(Bs + (wn + j * 16 + mfrag) * 64 + c0);
#pragma unroll
      for (int i = 0; i < 4; ++i)
#pragma unroll
        for (int j = 0; j < 4; ++j)
          acc[i][j] = __builtin_amdgcn_mfma_f32_16x16x32_f16(af[i], bfr[j], acc[i][j], 0, 0, 0);
    }
    __syncthreads();
  }
  float* Cc = C + (size_t)kc * chunkStride;
#pragma unroll
  for (int i = 0; i < 4; ++i)
#pragma unroll
    for (int j = 0; j < 4; ++j)
#pragma unroll
      for (int rr = 0; rr < 4; ++rr) {
        int row = m0 + wm + i * 16 + quad * 4 + rr;
        int col = n0 + wn + j * 16 + mfrag;
        Cc[(size_t)row * ldc + col] = acc[i][j][rr];
      }
}

// ---------------- attn@x causal GEMM: packed, size-balanced 1D grid --------------
// 768 real (bm,bn,kc) work items, sorted by descending K-work and snake-striped
// so each CU's ~3 blocks sum to ~66 BK-units regardless of assignment order.
__global__ __launch_bounds__(256, 4) void gemm_attnx(const u16* __restrict__ A,
                                                     const u16* __restrict__ B,
                                                     u16* __restrict__ C,
                                                     u16* __restrict__ Cf,
                                                     size_t chunkStride) {
  int b = blockIdx.x;
  int s = b >> 8, c = b & 255;
  int r = (s == 0) ? c : (s == 1) ? (511 - c) : (512 + c);
  int bm, bn, kc;
  if (r < 272) {
    bm = 15 + (r >> 4); bn = r & 15; kc = 0;
  } else if (r < 288) {
    bm = 31; bn = r - 272; kc = 1;
  } else {
    int g = (r - 288) >> 5, j = (r - 288) & 31;
    int k = 15 - g;
    if (j < 16) { bm = k - 1; bn = j; kc = 0; }
    else        { bm = 15 + k; bn = j - 16; kc = 1; }
  }
  int kEnd = (bm + 1) * 128;
  if (kEnd > NCTX) kEnd = NCTX;
  int kStart = kc * 2048;
  int kStop = kStart + 2048 < kEnd ? kStart + 2048 : kEnd;
  __shared__ __align__(16) u16 As[128 * 64];
  __shared__ __align__(16) u16 Bs[128 * 64];
  int t = threadIdx.x;
  int lane = t & 63, w = t >> 6;
  int m0 = bm * 128, n0 = bn * 128;
  int wm = (w >> 1) * 64, wn = (w & 1) * 64;
  int mfrag = lane & 15, quad = lane >> 4;
  int srow = t >> 3, schunk = t & 7;
  int rsw = mfrag & 7;
  f32x4 acc[4][4] = {};
  for (int kt = kStart; kt < kStop; kt += 64) {
#pragma unroll
    for (int p = 0; p < 4; ++p) {
      int row = p * 32 + srow;
      int gsc = schunk ^ (row & 7);
      gl_lds16(A + (size_t)(m0 + row) * NCTX + kt + gsc * 8, As + (size_t)(p * 256 + t) * 8);
      gl_lds16(B + (size_t)(n0 + row) * NCTX + kt + gsc * 8, Bs + (size_t)(p * 256 + t) * 8);
    }
    __syncthreads();
#pragma unroll
    for (int ks = 0; ks < 2; ++ks) {
      int c0 = ((ks * 4 + quad) ^ rsw) * 8;
      f16x8 af[4], bfr[4];
#pragma unroll
      for (int i = 0; i < 4; ++i)
        af[i] = *(const f16x8*)(As + (wm + i * 16 + mfrag) * 64 + c0);
#pragma unroll
      for (int j = 0; j < 4; ++j)
        bfr[j] = *(const f16x8*)(Bs + (wn + j * 16 + mfrag) * 64 + c0);
#pragma unroll
      for (int i = 0; i < 4; ++i)
#pragma unroll
        for (int j = 0; j < 4; ++j)
          acc[i][j] = __builtin_amdgcn_mfma_f32_16x16x32_f16(af[i], bfr[j], acc[i][j], 0, 0, 0);
    }
    __syncthreads();
  }
  // bm<16: chunk covers whole causal K -> final-direct to Cf; else f16 partial.
  u16* Cc = (kc == 0 && kEnd <= 2048) ? Cf : (C + (size_t)kc * chunkStride);
#pragma unroll
  for (int i = 0; i < 4; ++i)
#pragma unroll
    for (int j = 0; j < 4; ++j)
#pragma unroll
      for (int rr = 0; rr < 4; ++rr) {
        int row = m0 + wm + i * 16 + quad * 4 + rr;
        int col = n0 + wn + j * 16 + mfrag;
        Cc[(size_t)row * DMODEL + col] = f2h(acc[i][j][rr]);
      }
}

// ---------------- f16x2 split-A MFMA GEMM (qk projection), f16 partials ----------
__global__ __launch_bounds__(256, 3) void gemm_f16x2_p(const u16* __restrict__ Ah,
                                                       const u16* __restrict__ Al,
                                                       const u16* __restrict__ B,
                                                       u16* __restrict__ C,
                                                       int lda, int ldb, int ldc,
                                                       int K, int KC, size_t chunkStride) {
  int bm = blockIdx.x, bn = blockIdx.y, kc = blockIdx.z;
  int kStart = kc * KC;
  int kStop = kStart + KC < K ? kStart + KC : K;
  __shared__ __align__(16) u16 Ash[128 * 64];
  __shared__ __align__(16) u16 Asl[128 * 64];
  __shared__ __align__(16) u16 Bs[128 * 64];
  int t = threadIdx.x;
  int lane = t & 63, w = t >> 6;
  int m0 = bm * 128, n0 = bn * 128;
  int wm = (w >> 1) * 64, wn = (w & 1) * 64;
  int mfrag = lane & 15, quad = lane >> 4;
  int srow = t >> 3, schunk = t & 7;
  int rsw = mfrag & 7;
  f32x4 acc[4][4] = {};
  for (int kt = kStart; kt < kStop; kt += 64) {
#pragma unroll
    for (int p = 0; p < 4; ++p) {
      int row = p * 32 + srow;
      int gsc = schunk ^ (row & 7);
      size_t aoff = (size_t)(m0 + row) * lda + kt + gsc * 8;
      size_t loff = (size_t)(p * 256 + t) * 8;
      gl_lds16(Ah + aoff, Ash + loff);
      gl_lds16(Al + aoff, Asl + loff);
      gl_lds16(B + (size_t)(n0 + row) * ldb + kt + gsc * 8, Bs + loff);
    }
    __syncthreads();
#pragma unroll
    for (int ks = 0; ks < 2; ++ks) {
      int c0 = ((ks * 4 + quad) ^ rsw) * 8;
      f16x8 a0[4], bfr[4];
#pragma unroll
      for (int j = 0; j < 4; ++j)
        bfr[j] = *(const f16x8*)(Bs + (wn + j * 16 + mfrag) * 64 + c0);
#pragma unroll
      for (int i = 0; i < 4; ++i)
        a0[i] = *(const f16x8*)(Ash + (wm + i * 16 + mfrag) * 64 + c0);
#pragma unroll
      for (int i = 0; i < 4; ++i)
#pragma unroll
        for (int j = 0; j < 4; ++j)
          acc[i][j] = __builtin_amdgcn_mfma_f32_16x16x32_f16(a0[i], bfr[j], acc[i][j], 0, 0, 0);
#pragma unroll
      for (int i = 0; i < 4; ++i)
        a0[i] = *(const f16x8*)(Asl + (wm + i * 16 + mfrag) * 64 + c0);
#pragma unroll
      for (int i = 0; i < 4; ++i)
#pragma unroll
        for (int j = 0; j < 4; ++j)
          acc[i][j] = __builtin_amdgcn_mfma_f32_16x16x32_f16(a0[i], bfr[j], acc[i][j], 0, 0, 0);
    }
    __syncthreads();
  }
  u16* Cc = C + (size_t)kc * chunkStride;
#pragma unroll
  for (int i = 0; i < 4; ++i)
#pragma unroll
    for (int j = 0; j < 4; ++j)
#pragma unroll
      for (int rr = 0; rr < 4; ++rr) {
        int row = m0 + wm + i * 16 + quad * 4 + rr;
        int col = n0 + wn + j * 16 + mfrag;
        Cc[(size_t)row * ldc + col] = f2h(acc[i][j][rr]);
      }
}

extern "C" void kernel_launch(void* const* d_in, const int* in_sizes, int n_in,
                              void* d_out, int out_size, void* d_ws, size_t ws_size,
                              hipStream_t stream) {
  const float* x  = (const float*)d_in[0];
  const float* Wk = (const float*)d_in[1];
  const float* Wq = (const float*)d_in[2];
  const float* W2 = (const float*)d_in[3];

  char* ws = (char*)d_ws;
  const size_t MB = 1024 * 1024;
  // persistent region [0, 75 MB)
  u16*   QKf  = (u16*)  (ws + 0);            //  2 MB  [4096,256] f16 (q | k)
  u16*   Wf   = (u16*)  (ws + 2 * MB);       //  1 MB  [256,2048] (Wq ; Wk) f16
  u16*   xT   = (u16*)  (ws + 3 * MB);       // 16 MB  [2048,4096] f16
  u16*   W2f  = (u16*)  (ws + 19 * MB);      //  8 MB  [2048,2048] f16
  u16*   outb = (u16*)  (ws + 27 * MB);      // 16 MB  [4096,2048] f16
  u16*   attn = (u16*)  (ws + 43 * MB);      // 32 MB  [4096,4096] f16
  // reusable region A [75, 139 MB) — lifetimes strictly sequential:
  u16*   xh   = (u16*)  (ws + 75 * MB);      // 16 MB  (dead after qk gemm)
  u16*   xl   = (u16*)  (ws + 91 * MB);      // 16 MB  (dead after qk gemm)
  u16*   QKp  = (u16*)  (ws + 107 * MB);     // 16 MB  8 x [4096,256] f16 partials
  float* S    = (float*)(ws + 75 * MB);      // 64 MB  scores (after xh/xl/QKp dead)
  u16*   Ph   = (u16*)  (ws + 75 * MB);      // 32 MB  2 x [4096,2048] f16 partials (after S dead)

  const int QKN8 = NCTX * 256 / 8;
  const size_t CS = (size_t)NCTX * DMODEL;   // partial chunk stride (elements)

  // fused prep: x f16-split + f16 transpose + W/W2 casts
  prep_all<<<6656, 256, 0, stream>>>(x, Wq, Wk, W2, xh, xl, Wf, W2f, xT);

  // q,k = (xh+xl) @ [Wq;Wk]^T  (f16x2 2-pass), split-K KC=256, f16 partials
  gemm_f16x2_p<<<dim3(NCTX / 128, 2, 8), 256, 0, stream>>>(
      xh, xl, Wf, QKp, DMODEL, DMODEL, 256, DMODEL, 256, (size_t)NCTX * 256);
  reduce8h<<<(QKN8 + 255) / 256, 256, 0, stream>>>(QKp, QKf, QKN8);

  // scores = q @ k^T, single-pass f16, lower-triangular tiles, direct fp32 store
  gemm_f16_p<<<dim3(NCTX / 128, NCTX / 128, 1), 256, 0, stream>>>(
      QKf, QKf + DHEAD, S, 256, 256, NCTX, DHEAD, DHEAD, 0, 0, 1);
  softmax_wave<<<1024, 256, 0, stream>>>(S, attn);

  // out = attn @ x (causal): packed 768-block balanced grid; rows<2048
  // final-direct to outb, rows>=2048 f16 partials -> reduce_c2
  gemm_attnx<<<768, 256, 0, stream>>>(attn, xT, Ph, outb, CS);
  reduce_c2<<<2048, 256, 0, stream>>>(Ph, outb, CS);

  // final = out @ W2^T: z=1, K=2048 unsplit, direct fp32 store to d_out
  gemm_f16_p<<<dim3(NCTX / 128, DMODEL / 128, 1), 256, 0, stream>>>(
      outb, W2f, (float*)d_out, DMODEL, DMODEL, DMODEL, DMODEL, DMODEL, 0, 0, 0);
}